// Round 1
// baseline (1673.105 us; speedup 1.0000x reference)
//
#include <hip/hip_runtime.h>

#define BB 8
#define NN 4096
#define DD 64
#define SS 1024
#define KK 32
#define GINF 1e30f

__device__ __forceinline__ float fmulrn(float a, float b){ return __fmul_rn(a,b); }
__device__ __forceinline__ float faddrn(float a, float b){ return __fadd_rn(a,b); }
__device__ __forceinline__ float fsubrn(float a, float b){ return __fsub_rn(a,b); }

// ---------------- |x|^2 precompute (exact op order: ((x*x + y*y) + z*z)) ----------------
__global__ __launch_bounds__(256) void sqx_kernel(const float* __restrict__ xyz,
                                                  float* __restrict__ sqx){
  int i = blockIdx.x * 256 + threadIdx.x;         // 0 .. B*N-1
  int b = i >> 12, n = i & (NN - 1);
  const float* xb = xyz + b * 3 * NN;
  float x = xb[n], y = xb[NN + n], z = xb[2 * NN + n];
  sqx[i] = faddrn(faddrn(fmulrn(x, x), fmulrn(y, y)), fmulrn(z, z));
}

// ---------------- Farthest point sampling: 1 block per batch ----------------
__global__ __launch_bounds__(512) void fps_kernel(const float* __restrict__ xyz,
                                                  const int* __restrict__ finit,
                                                  int* __restrict__ fps_idx){
  __shared__ float lx[NN], ly[NN], lz[NN];   // 48 KB coord table
  __shared__ float pv[16];                   // 8 wave partials x 2 parity
  __shared__ int   pn[16];
  int b = blockIdx.x, tid = threadIdx.x;
  const float* xb = xyz + b * 3 * NN;
  float px[8], py[8], pz[8], dist[8];
  #pragma unroll
  for (int k = 0; k < 8; ++k){
    int n = k * 512 + tid;                   // coalesced
    px[k] = xb[n]; py[k] = xb[NN + n]; pz[k] = xb[2 * NN + n];
    lx[n] = px[k]; ly[n] = py[k]; lz[n] = pz[k];
    dist[k] = 1e10f;                         // matches jnp.full(..., 1e10, f32)
  }
  int far = finit[b];
  if (tid == 0) fps_idx[b * SS] = far;       // scan collects far BEFORE update
  __syncthreads();

  for (int it = 0; it < SS - 1; ++it){
    float cx = lx[far], cy = ly[far], cz = lz[far];
    float bv = -1.0f; int bn = 0;
    #pragma unroll
    for (int k = 0; k < 8; ++k){
      // d = ((x-cx)^2 + (y-cy)^2) + (z-cz)^2, exact IEEE ops, no FMA
      float tx = fsubrn(px[k], cx), ty = fsubrn(py[k], cy), tz = fsubrn(pz[k], cz);
      float d2 = faddrn(faddrn(fmulrn(tx, tx), fmulrn(ty, ty)), fmulrn(tz, tz));
      float dk = fminf(dist[k], d2);
      dist[k] = dk;
      if (dk > bv){ bv = dk; bn = k * 512 + tid; }   // strict >: first (smallest-n) max kept
    }
    // wave lex-argmax (value desc, index asc on ties)
    #pragma unroll
    for (int m = 1; m < 64; m <<= 1){
      float ov = __shfl_xor(bv, m);
      int   on = __shfl_xor(bn, m);
      if (ov > bv || (ov == bv && on < bn)){ bv = ov; bn = on; }
    }
    int par = (it & 1) << 3;
    int wid = tid >> 6;
    if ((tid & 63) == 0){ pv[par + wid] = bv; pn[par + wid] = bn; }
    __syncthreads();                          // single barrier/iter (parity dbl-buffer)
    bv = pv[par]; bn = pn[par];
    #pragma unroll
    for (int w = 1; w < 8; ++w){
      float sv = pv[par + w]; int sn = pn[par + w];
      if (sv > bv || (sv == bv && sn < bn)){ bv = sv; bn = sn; }
    }
    far = bn;
    if (tid == 0) fps_idx[b * SS + it + 1] = far;
  }
}

// ---------------- kNN (top-32 by expanded sq-dist) + gather + feature max ----------------
// one wave per centroid; d[64] static in registers; 8-group tournament extraction
__global__ __launch_bounds__(256) void knn_kernel(const float* __restrict__ xyz,
                                                  const float* __restrict__ points,
                                                  const float* __restrict__ sqx,
                                                  const int* __restrict__ fps_idx,
                                                  float* __restrict__ out){
  __shared__ int nbr[4][KK];
  int tid = threadIdx.x;
  int lane = tid & 63, wslot = tid >> 6;
  int gw = blockIdx.x * 4 + wslot;           // 0 .. 8191
  int b = gw >> 10, cs = gw & 1023;
  const float* xb = xyz + b * 3 * NN;
  const float* sb = sqx + b * NN;
  int c0 = fps_idx[b * SS + cs];
  float cx = xb[c0], cy = xb[NN + c0], cz = xb[2 * NN + c0];
  float sqc = sb[c0];

  float d[64];
  #pragma unroll
  for (int k = 0; k < 64; ++k){
    int n = (k << 6) | lane;                 // coalesced: lane-consecutive
    float xn = xb[n], yn = xb[NN + n], zn = xb[2 * NN + n], sn = sb[n];
    // sq = (sqc + sqx[n]) - 2*((cx*x + cy*y) + cz*z), exact IEEE, no FMA
    float dot = faddrn(faddrn(fmulrn(cx, xn), fmulrn(cy, yn)), fmulrn(cz, zn));
    d[k] = fsubrn(faddrn(sqc, sn), fmulrn(2.0f, dot));
  }

  // per-lane 8-group mins (lex (d,n), ascending n within lane -> strict <)
  float gv[8]; int gn[8];
  #pragma unroll
  for (int j = 0; j < 8; ++j){
    float nv = GINF; int nn2 = 0x40000000;
    #pragma unroll
    for (int t = 0; t < 8; ++t){
      int k = j * 8 + t; int n = (k << 6) | lane;
      if (d[k] < nv){ nv = d[k]; nn2 = n; }
    }
    gv[j] = nv; gn[j] = nn2;
  }

  float lv = -GINF; int ln = -1;             // last extracted (lex filter)
  for (int r = 0; r < KK; ++r){
    float bv = gv[0]; int bn = gn[0];
    #pragma unroll
    for (int j = 1; j < 8; ++j){ if (gv[j] < bv){ bv = gv[j]; bn = gn[j]; } }
    // wave lex-argmin (value asc, index asc on ties) == lax.top_k tie rule
    #pragma unroll
    for (int m = 1; m < 64; m <<= 1){
      float ov = __shfl_xor(bv, m);
      int   on = __shfl_xor(bn, m);
      if (ov < bv || (ov == bv && on < bn)){ bv = ov; bn = on; }
    }
    if (lane == 0) nbr[wslot][r] = bn;
    lv = bv; ln = bn;
    int jsel = __builtin_amdgcn_readfirstlane(bn >> 9);  // group of extracted elem
    // recompute only that group, all lanes, under filter (d,n) >lex (lv,ln)
    #define RECOMP(J) if (jsel == (J)) { float nv = GINF; int nn2 = 0x40000000; \
      _Pragma("unroll") \
      for (int t = 0; t < 8; ++t){ int k = (J) * 8 + t; int n = (k << 6) | lane; \
        bool pass = (d[k] > lv) || (d[k] == lv && n > ln); \
        if (pass && d[k] < nv){ nv = d[k]; nn2 = n; } } \
      gv[(J)] = nv; gn[(J)] = nn2; }
    RECOMP(0) RECOMP(1) RECOMP(2) RECOMP(3)
    RECOMP(4) RECOMP(5) RECOMP(6) RECOMP(7)
    #undef RECOMP
  }
  __syncthreads();

  // gather + max-pool: lane = feature d; xyz maxes tracked redundantly (broadcast loads)
  const float* pb = points + b * DD * NN;
  float fm = -GINF, xm = -GINF, ym = -GINF, zm = -GINF;
  #pragma unroll 8
  for (int j = 0; j < KK; ++j){
    int nj = nbr[wslot][j];
    fm = fmaxf(fm, pb[lane * NN + nj]);
    xm = fmaxf(xm, xb[nj]);
    ym = fmaxf(ym, xb[NN + nj]);
    zm = fmaxf(zm, xb[2 * NN + nj]);
  }
  float* out1 = out + BB * 3 * SS;           // (B,67,S) after (B,3,S)
  float* o1b  = out1 + b * 67 * SS;
  o1b[(3 + lane) * SS + cs] = fm;
  if (lane == 0){
    o1b[cs] = xm; o1b[SS + cs] = ym; o1b[2 * SS + cs] = zm;
    float* o0b = out + b * 3 * SS;
    o0b[cs] = cx; o0b[SS + cs] = cy; o0b[2 * SS + cs] = cz;
  }
}

extern "C" void kernel_launch(void* const* d_in, const int* in_sizes, int n_in,
                              void* d_out, int out_size, void* d_ws, size_t ws_size,
                              hipStream_t stream){
  const float* xyz    = (const float*)d_in[0];
  const float* points = (const float*)d_in[1];
  const int*   finit  = (const int*)d_in[2];
  float* out = (float*)d_out;
  int*   fps_idx = (int*)d_ws;                               // 8*1024 ints
  float* sqx     = (float*)((char*)d_ws + BB * SS * sizeof(int)); // 8*4096 floats

  hipLaunchKernelGGL(sqx_kernel, dim3(BB * NN / 256), dim3(256), 0, stream, xyz, sqx);
  hipLaunchKernelGGL(fps_kernel, dim3(BB), dim3(512), 0, stream, xyz, finit, fps_idx);
  hipLaunchKernelGGL(knn_kernel, dim3(BB * SS / 4), dim3(256), 0, stream,
                     xyz, points, sqx, fps_idx, out);
}

// Round 2
// 1147.411 us; speedup vs baseline: 1.4582x; 1.4582x over previous
//
#include <hip/hip_runtime.h>

#define BB 8
#define NN 4096
#define DD 64
#define SS 1024
#define KK 32
#define GINF 1e30f

__device__ __forceinline__ float fmulrn(float a, float b){ return __fmul_rn(a,b); }
__device__ __forceinline__ float faddrn(float a, float b){ return __fadd_rn(a,b); }
__device__ __forceinline__ float fsubrn(float a, float b){ return __fsub_rn(a,b); }

// one DPP max step: v_mov_b32_dpp (zero-fill OOB, valid since dists >= 0) + v_max_f32
template<int CTRL>
__device__ __forceinline__ float dpp_fmax(float v){
  int o = __builtin_amdgcn_update_dpp(0, __float_as_int(v), CTRL, 0xf, 0xf, true);
  return fmaxf(v, __int_as_float(o));
}

// ---------------- |x|^2 precompute (exact op order: ((x*x + y*y) + z*z)) ----------------
__global__ __launch_bounds__(256) void sqx_kernel(const float* __restrict__ xyz,
                                                  float* __restrict__ sqx){
  int i = blockIdx.x * 256 + threadIdx.x;         // 0 .. B*N-1
  int b = i >> 12, n = i & (NN - 1);
  const float* xb = xyz + b * 3 * NN;
  float x = xb[n], y = xb[NN + n], z = xb[2 * NN + n];
  sqx[i] = faddrn(faddrn(fmulrn(x, x), fmulrn(y, y)), fmulrn(z, z));
}

// ---------------- Farthest point sampling: 1 block (4 waves) per batch ----------------
// lane-major layout: thread t owns points [t*16, t*16+16)  ->  first-set-lane == smallest n
__global__ __launch_bounds__(256) void fps_kernel(const float* __restrict__ xyz,
                                                  const int* __restrict__ finit,
                                                  int* __restrict__ fps_idx){
  __shared__ float4 sc[2][4];   // per-wave candidate {cx,cy,cz,val}, parity dbl-buffered
  __shared__ int    sn[2][4];   // per-wave candidate n
  int b = blockIdx.x, tid = threadIdx.x;
  int lane = tid & 63, w = tid >> 6;
  const float* xb = xyz + b * 3 * NN;
  float px[16], py[16], pz[16], dist[16];
  int nbase = tid << 4;
  #pragma unroll
  for (int j = 0; j < 16; ++j){
    px[j] = xb[nbase + j];
    py[j] = xb[NN + nbase + j];
    pz[j] = xb[2 * NN + nbase + j];
    dist[j] = 1e10f;                       // matches jnp.full(..., 1e10, f32)
  }
  int far = finit[b];
  float cx = xb[far], cy = xb[NN + far], cz = xb[2 * NN + far];  // iter-0 centroid (broadcast)
  if (tid == 0) fps_idx[b * SS] = far;

  for (int it = 0; it < SS - 1; ++it){
    // ---- update dists + per-lane max (no index tracking: deferred to rescan) ----
    float lm = 0.0f;                       // 0 is a valid identity: dists >= 0
    #pragma unroll
    for (int j = 0; j < 16; ++j){
      // d = ((x-cx)^2 + (y-cy)^2) + (z-cz)^2, exact IEEE ops, no FMA
      float tx = fsubrn(px[j], cx), ty = fsubrn(py[j], cy), tz = fsubrn(pz[j], cz);
      float d2 = faddrn(faddrn(fmulrn(tx, tx), fmulrn(ty, ty)), fmulrn(tz, tz));
      float dk = fminf(dist[j], d2);
      dist[j] = dk;
      lm = fmaxf(lm, dk);
    }
    // ---- wave max via DPP tree (VALU latency, replaces ds_bpermute shfl chain) ----
    float v = lm;
    v = dpp_fmax<0x111>(v);   // row_shr:1
    v = dpp_fmax<0x112>(v);   // row_shr:2
    v = dpp_fmax<0x114>(v);   // row_shr:4
    v = dpp_fmax<0x118>(v);   // row_shr:8
    v = dpp_fmax<0x142>(v);   // row_bcast:15
    v = dpp_fmax<0x143>(v);   // row_bcast:31  -> lane 63 has wave max
    float maxv = __int_as_float(__builtin_amdgcn_readlane(__float_as_int(v), 63));
    // ---- first-match rescan (exact bit equality; max is bitwise one of the dists) ----
    int loc = 16;
    float scx = 0.f, scy = 0.f, scz = 0.f;
    #pragma unroll
    for (int j = 15; j >= 0; --j){
      if (dist[j] == maxv){ loc = j; scx = px[j]; scy = py[j]; scz = pz[j]; }
    }
    unsigned long long bal = __ballot(loc < 16);
    int fl = __ffsll(bal) - 1;            // first matching lane == smallest n in wave
    int par = it & 1;
    if (lane == fl){                       // winning lane writes coords+val+n from its regs
      sc[par][w] = make_float4(scx, scy, scz, maxv);
      sn[par][w] = nbase + loc;
    }
    __syncthreads();                       // single barrier/iter (parity dbl-buffer)
    float4 s0 = sc[par][0]; int n0 = sn[par][0];
    #pragma unroll
    for (int q = 1; q < 4; ++q){
      float4 sq_ = sc[par][q]; int nq = sn[par][q];
      if (sq_.w > s0.w || (sq_.w == s0.w && nq < n0)){ s0 = sq_; n0 = nq; }
    }
    cx = s0.x; cy = s0.y; cz = s0.z; far = n0;
    if (tid == 0) fps_idx[b * SS + it + 1] = far;
  }
}

// ---------------- kNN (top-32 by expanded sq-dist) + gather + feature max ----------------
// one wave per centroid; d[64] static in registers; 8-group tournament extraction
__global__ __launch_bounds__(256) void knn_kernel(const float* __restrict__ xyz,
                                                  const float* __restrict__ points,
                                                  const float* __restrict__ sqx,
                                                  const int* __restrict__ fps_idx,
                                                  float* __restrict__ out){
  __shared__ int nbr[4][KK];
  int tid = threadIdx.x;
  int lane = tid & 63, wslot = tid >> 6;
  int gw = blockIdx.x * 4 + wslot;           // 0 .. 8191
  int b = gw >> 10, cs = gw & 1023;
  const float* xb = xyz + b * 3 * NN;
  const float* sb = sqx + b * NN;
  int c0 = fps_idx[b * SS + cs];
  float cx = xb[c0], cy = xb[NN + c0], cz = xb[2 * NN + c0];
  float sqc = sb[c0];

  float d[64];
  #pragma unroll
  for (int k = 0; k < 64; ++k){
    int n = (k << 6) | lane;                 // coalesced: lane-consecutive
    float xn = xb[n], yn = xb[NN + n], zn = xb[2 * NN + n], sn = sb[n];
    // sq = (sqc + sqx[n]) - 2*((cx*x + cy*y) + cz*z), exact IEEE, no FMA
    float dot = faddrn(faddrn(fmulrn(cx, xn), fmulrn(cy, yn)), fmulrn(cz, zn));
    d[k] = fsubrn(faddrn(sqc, sn), fmulrn(2.0f, dot));
  }

  // per-lane 8-group mins (lex (d,n), ascending n within lane -> strict <)
  float gv[8]; int gn[8];
  #pragma unroll
  for (int j = 0; j < 8; ++j){
    float nv = GINF; int nn2 = 0x40000000;
    #pragma unroll
    for (int t = 0; t < 8; ++t){
      int k = j * 8 + t; int n = (k << 6) | lane;
      if (d[k] < nv){ nv = d[k]; nn2 = n; }
    }
    gv[j] = nv; gn[j] = nn2;
  }

  float lv = -GINF; int ln = -1;             // last extracted (lex filter)
  for (int r = 0; r < KK; ++r){
    float bv = gv[0]; int bn = gn[0];
    #pragma unroll
    for (int j = 1; j < 8; ++j){ if (gv[j] < bv){ bv = gv[j]; bn = gn[j]; } }
    // wave lex-argmin (value asc, index asc on ties) == lax.top_k tie rule
    #pragma unroll
    for (int m = 1; m < 64; m <<= 1){
      float ov = __shfl_xor(bv, m);
      int   on = __shfl_xor(bn, m);
      if (ov < bv || (ov == bv && on < bn)){ bv = ov; bn = on; }
    }
    if (lane == 0) nbr[wslot][r] = bn;
    lv = bv; ln = bn;
    int jsel = __builtin_amdgcn_readfirstlane(bn >> 9);  // group of extracted elem
    // recompute only that group, all lanes, under filter (d,n) >lex (lv,ln)
    #define RECOMP(J) if (jsel == (J)) { float nv = GINF; int nn2 = 0x40000000; \
      _Pragma("unroll") \
      for (int t = 0; t < 8; ++t){ int k = (J) * 8 + t; int n = (k << 6) | lane; \
        bool pass = (d[k] > lv) || (d[k] == lv && n > ln); \
        if (pass && d[k] < nv){ nv = d[k]; nn2 = n; } } \
      gv[(J)] = nv; gn[(J)] = nn2; }
    RECOMP(0) RECOMP(1) RECOMP(2) RECOMP(3)
    RECOMP(4) RECOMP(5) RECOMP(6) RECOMP(7)
    #undef RECOMP
  }
  __syncthreads();

  // gather + max-pool: lane = feature d; xyz maxes tracked redundantly (broadcast loads)
  const float* pb = points + b * DD * NN;
  float fm = -GINF, xm = -GINF, ym = -GINF, zm = -GINF;
  #pragma unroll 8
  for (int j = 0; j < KK; ++j){
    int nj = nbr[wslot][j];
    fm = fmaxf(fm, pb[lane * NN + nj]);
    xm = fmaxf(xm, xb[nj]);
    ym = fmaxf(ym, xb[NN + nj]);
    zm = fmaxf(zm, xb[2 * NN + nj]);
  }
  float* out1 = out + BB * 3 * SS;           // (B,67,S) after (B,3,S)
  float* o1b  = out1 + b * 67 * SS;
  o1b[(3 + lane) * SS + cs] = fm;
  if (lane == 0){
    o1b[cs] = xm; o1b[SS + cs] = ym; o1b[2 * SS + cs] = zm;
    float* o0b = out + b * 3 * SS;
    o0b[cs] = cx; o0b[SS + cs] = cy; o0b[2 * SS + cs] = cz;
  }
}

extern "C" void kernel_launch(void* const* d_in, const int* in_sizes, int n_in,
                              void* d_out, int out_size, void* d_ws, size_t ws_size,
                              hipStream_t stream){
  const float* xyz    = (const float*)d_in[0];
  const float* points = (const float*)d_in[1];
  const int*   finit  = (const int*)d_in[2];
  float* out = (float*)d_out;
  int*   fps_idx = (int*)d_ws;                               // 8*1024 ints
  float* sqx     = (float*)((char*)d_ws + BB * SS * sizeof(int)); // 8*4096 floats

  hipLaunchKernelGGL(sqx_kernel, dim3(BB * NN / 256), dim3(256), 0, stream, xyz, sqx);
  hipLaunchKernelGGL(fps_kernel, dim3(BB), dim3(256), 0, stream, xyz, finit, fps_idx);
  hipLaunchKernelGGL(knn_kernel, dim3(BB * SS / 4), dim3(256), 0, stream,
                     xyz, points, sqx, fps_idx, out);
}